// Round 1
// baseline (864.967 us; speedup 1.0000x reference)
//
#include <hip/hip_runtime.h>
#include <math.h>

#define HDIM 128

typedef _Float16 f16;
typedef unsigned short u16;
typedef __attribute__((ext_vector_type(2))) _Float16 f16x2;
typedef __attribute__((ext_vector_type(4))) _Float16 f16x4;
typedef __attribute__((ext_vector_type(8))) _Float16 f16x8;
typedef __attribute__((ext_vector_type(4))) float f32x4;

// ================= CSR build =================
// counts in-degree AND records each edge's rank within its dst bucket
__global__ __launch_bounds__(256) void degrank_kernel(
    const int* __restrict__ edg, int* __restrict__ deg,
    u16* __restrict__ rank, int E) {
  int e = blockIdx.x * 256 + threadIdx.x;
  if (e < E) rank[e] = (u16)atomicAdd(&deg[edg[E + e]], 1);
}

__global__ __launch_bounds__(256) void scan_part_kernel(
    const int* __restrict__ deg, int* __restrict__ bsum, int n, int chunk) {
  __shared__ int red[256];
  const int b = blockIdx.x, t = threadIdx.x;
  const int begin = b * chunk;
  const int end = min(begin + chunk, n);
  int s = 0;
  for (int i = begin + t; i < end; i += 256) s += deg[i];
  red[t] = s;
  __syncthreads();
  for (int off = 128; off > 0; off >>= 1) {
    if (t < off) red[t] += red[t + off];
    __syncthreads();
  }
  if (t == 0) bsum[b] = red[0];
}

__global__ __launch_bounds__(256) void scan_top_kernel(
    const int* __restrict__ bsum, int* __restrict__ boff,
    int* __restrict__ offs, int n) {
  __shared__ int sh[256];
  const int t = threadIdx.x;
  int v = bsum[t];
  sh[t] = v;
  __syncthreads();
  for (int off = 1; off < 256; off <<= 1) {
    int add = (t >= off) ? sh[t - off] : 0;
    __syncthreads();
    sh[t] += add;
    __syncthreads();
  }
  boff[t] = sh[t] - v;
  if (t == 255) offs[n] = sh[255];
}

__global__ __launch_bounds__(256) void scan_fin_kernel(
    const int* __restrict__ deg, const int* __restrict__ boff,
    int* __restrict__ offs, int n, int chunk) {
  __shared__ int sh[256];
  const int b = blockIdx.x, t = threadIdx.x;
  const int idx = b * chunk + t;
  int v = (t < chunk && idx < n) ? deg[idx] : 0;
  sh[t] = v;
  __syncthreads();
  for (int off = 1; off < 256; off <<= 1) {
    int add = (t >= off) ? sh[t - off] : 0;
    __syncthreads();
    sh[t] += add;
    __syncthreads();
  }
  if (t < chunk && idx < n) offs[idx] = boff[b] + sh[t] - v;
}

// atomic-free fill: pos = offs[dst] + rank[e]; u16 scattered store
__global__ __launch_bounds__(256) void fill_kernel(
    const int* __restrict__ edg, const int* __restrict__ offs,
    const u16* __restrict__ rank, u16* __restrict__ csr_src, int E) {
  int i = blockIdx.x * 256 + threadIdx.x;
  int e0 = i * 4;
  if (e0 >= E) return;
  if (e0 + 4 <= E) {
    int4 s4 = *reinterpret_cast<const int4*>(edg + e0);
    int4 d4 = *reinterpret_cast<const int4*>(edg + E + e0);
    ushort4 r4 = *reinterpret_cast<const ushort4*>(rank + e0);
    csr_src[offs[d4.x] + r4.x] = (u16)s4.x;
    csr_src[offs[d4.y] + r4.y] = (u16)s4.y;
    csr_src[offs[d4.z] + r4.z] = (u16)s4.z;
    csr_src[offs[d4.w] + r4.w] = (u16)s4.w;
  } else {
    for (int e = e0; e < E; ++e)
      csr_src[offs[edg[E + e]] + rank[e]] = (u16)edg[e];
  }
}

// sort each dst bucket by src ascending — concurrent waves then walk src in
// roughly synchronized order => smaller instantaneous gather working set
__global__ __launch_bounds__(64) void sort_kernel(
    const int* __restrict__ offs, u16* __restrict__ csr_src, int N) {
  __shared__ u16 buf[64][100];
  int node = blockIdx.x * 64 + threadIdx.x;
  if (node >= N) return;
  int s = offs[node], e = offs[node + 1];
  int d = e - s;
  if (d <= 1) return;
  if (d > 100) {  // pathological degree: in-place global fallback
    for (int i = s + 1; i < e; ++i) {
      u16 v = csr_src[i];
      int j = i - 1;
      while (j >= s && csr_src[j] > v) { csr_src[j + 1] = csr_src[j]; --j; }
      csr_src[j + 1] = v;
    }
    return;
  }
  u16* b = buf[threadIdx.x];
  for (int i = 0; i < d; ++i) b[i] = csr_src[s + i];
  for (int i = 1; i < d; ++i) {
    u16 v = b[i];
    int j = i - 1;
    while (j >= 0 && b[j] > v) { b[j + 1] = b[j]; --j; }
    b[j + 1] = v;
  }
  for (int i = 0; i < d; ++i) csr_src[s + i] = b[i];
}

// ================= fp32 -> fp16 conversion =================
__global__ __launch_bounds__(256) void convh_kernel(
    const float* __restrict__ s, f16* __restrict__ d, int n4) {
  int i = blockIdx.x * 256 + threadIdx.x;
  if (i < n4) {
    float4 v = reinterpret_cast<const float4*>(s)[i];
    f16x4 o;
    o[0] = (f16)v.x; o[1] = (f16)v.y; o[2] = (f16)v.z; o[3] = (f16)v.w;
    reinterpret_cast<f16x4*>(d)[i] = o;
  }
}

// ================= W transpose + fp16: WT[gate][n][k] =================
__global__ __launch_bounds__(256) void transw_kernel(
    const float* __restrict__ W, f16* __restrict__ WT) {
  __shared__ float sh[32][33];
  const int g = blockIdx.y;
  const int ti = blockIdx.x >> 2;
  const int tj = blockIdx.x & 3;
  const float* __restrict__ wp = W + (size_t)g * HDIM * HDIM;
  f16* __restrict__ op = WT + (size_t)g * HDIM * HDIM;
  const int t = threadIdx.x;
  #pragma unroll
  for (int it = 0; it < 4; ++it) {
    int elem = it * 256 + t;
    int r = elem >> 5, c = elem & 31;
    sh[r][c] = wp[(size_t)(ti * 32 + r) * HDIM + tj * 32 + c];
  }
  __syncthreads();
  #pragma unroll
  for (int it = 0; it < 4; ++it) {
    int elem = it * 256 + t;
    int cc = elem >> 5, rr = elem & 31;
    op[(size_t)(tj * 32 + cc) * HDIM + ti * 32 + rr] = (f16)sh[rr][cc];
  }
}

// ================= pull aggregation =================
// wave = 1 node. lanes split: half (lane>>5) picks table {x,h}; within a half,
// sub=(lane>>4)&1 picks edge parity; 16 lanes x f16x8 = one 256B row.
// 8 row-loads of 16B/lane in flight per wave (vs 4x8B before).
__global__ __launch_bounds__(256) void pull2_kernel(
    const u16* __restrict__ csr_src, const int* __restrict__ offs,
    const f16* __restrict__ xb, const f16* __restrict__ hb,
    f16* __restrict__ A, f16* __restrict__ Bh, int N) {
  const int node = blockIdx.x * 4 + (threadIdx.x >> 6);
  if (node >= N) return;
  const int lane = threadIdx.x & 63;
  const int half = lane >> 5;
  const int sub = (lane >> 4) & 1;
  const int c = (lane & 15) << 3;
  const f16* __restrict__ nb = half ? hb : xb;
  f16* __restrict__ dst = half ? Bh : A;
  const int s = offs[node];
  const int e = offs[node + 1];
  float acc[8];
  if (sub == 0) {
    f16x8 sv = *reinterpret_cast<const f16x8*>(nb + (size_t)node * HDIM + c);
    #pragma unroll
    for (int q = 0; q < 8; ++q) acc[q] = (float)sv[q];
  } else {
    #pragma unroll
    for (int q = 0; q < 8; ++q) acc[q] = 0.f;
  }
  int k = s;
  for (; k + 8 <= e; k += 8) {
    int j0 = csr_src[k + sub];
    int j1 = csr_src[k + 2 + sub];
    int j2 = csr_src[k + 4 + sub];
    int j3 = csr_src[k + 6 + sub];
    f16x8 u0 = *reinterpret_cast<const f16x8*>(nb + (size_t)j0 * HDIM + c);
    f16x8 u1 = *reinterpret_cast<const f16x8*>(nb + (size_t)j1 * HDIM + c);
    f16x8 u2 = *reinterpret_cast<const f16x8*>(nb + (size_t)j2 * HDIM + c);
    f16x8 u3 = *reinterpret_cast<const f16x8*>(nb + (size_t)j3 * HDIM + c);
    #pragma unroll
    for (int q = 0; q < 8; ++q)
      acc[q] += ((float)u0[q] + (float)u1[q]) + ((float)u2[q] + (float)u3[q]);
  }
  for (; k < e; k += 2) {
    int j = k + sub;
    if (j < e) {
      f16x8 u = *reinterpret_cast<const f16x8*>(nb + (size_t)csr_src[j] * HDIM + c);
      #pragma unroll
      for (int q = 0; q < 8; ++q) acc[q] += (float)u[q];
    }
  }
  #pragma unroll
  for (int q = 0; q < 8; ++q) acc[q] += __shfl_xor(acc[q], 16, 64);
  if (sub == 0) {
    f16x8 o;
    #pragma unroll
    for (int q = 0; q < 8; ++q) o[q] = (f16)acc[q];
    *reinterpret_cast<f16x8*>(dst + (size_t)node * HDIM + c) = o;
  }
}

// wave = 1 node, 4 edge-slots (sub=lane>>4), f16x8 per lane.
__global__ __launch_bounds__(256) void pull1_kernel(
    const u16* __restrict__ csr_src, const int* __restrict__ offs,
    const f16* __restrict__ cb, f16* __restrict__ Ctot, int N) {
  const int node = blockIdx.x * 4 + (threadIdx.x >> 6);
  if (node >= N) return;
  const int lane = threadIdx.x & 63;
  const int sub = lane >> 4;
  const int c = (lane & 15) << 3;
  const int s = offs[node];
  const int e = offs[node + 1];
  float acc[8];
  if (sub == 0) {
    f16x8 sv = *reinterpret_cast<const f16x8*>(cb + (size_t)node * HDIM + c);
    #pragma unroll
    for (int q = 0; q < 8; ++q) acc[q] = (float)sv[q];
  } else {
    #pragma unroll
    for (int q = 0; q < 8; ++q) acc[q] = 0.f;
  }
  int k = s;
  for (; k + 8 <= e; k += 8) {
    int j0 = csr_src[k + sub];
    int j1 = csr_src[k + 4 + sub];
    f16x8 u0 = *reinterpret_cast<const f16x8*>(cb + (size_t)j0 * HDIM + c);
    f16x8 u1 = *reinterpret_cast<const f16x8*>(cb + (size_t)j1 * HDIM + c);
    #pragma unroll
    for (int q = 0; q < 8; ++q) acc[q] += (float)u0[q] + (float)u1[q];
  }
  for (; k < e; k += 4) {
    int j = k + sub;
    if (j < e) {
      f16x8 u = *reinterpret_cast<const f16x8*>(cb + (size_t)csr_src[j] * HDIM + c);
      #pragma unroll
      for (int q = 0; q < 8; ++q) acc[q] += (float)u[q];
    }
  }
  #pragma unroll
  for (int q = 0; q < 8; ++q) {
    acc[q] += __shfl_xor(acc[q], 16, 64);
    acc[q] += __shfl_xor(acc[q], 32, 64);
  }
  if (sub == 0) {
    f16x8 o;
    #pragma unroll
    for (int q = 0; q < 8; ++q) o[q] = (f16)acc[q];
    *reinterpret_cast<f16x8*>(Ctot + (size_t)node * HDIM + c) = o;
  }
}

// ================= MFMA gate GEMM =================
__global__ __launch_bounds__(256, 3) void gemm3_kernel(
    const f16* __restrict__ A, const f16* __restrict__ Bh,
    const f16* __restrict__ WT, const float* __restrict__ b,
    const float* __restrict__ hi, f16* __restrict__ zb,
    f16* __restrict__ cb, float* __restrict__ hpre, int N) {
  __shared__ f16 As[64 * 136];
  __shared__ f16 Ws[128 * 136];
  const int t = threadIdx.x;
  const int w = t >> 6, wr = w >> 1, wc = w & 1;
  const int lane = t & 63, ln15 = lane & 15, quad = lane >> 4;
  const int row0 = blockIdx.x * 64;
  const int group = blockIdx.y;
  f32x4 acc[2][4];
  #pragma unroll
  for (int i = 0; i < 2; ++i)
    #pragma unroll
    for (int j = 0; j < 4; ++j) acc[i][j] = (f32x4){0.f, 0.f, 0.f, 0.f};

  const int nphase = (group < 2) ? 2 : 1;
  for (int phase = 0; phase < nphase; ++phase) {
    const f16* __restrict__ src = phase ? Bh : A;
    const f16* __restrict__ wp = WT + (size_t)(group * 2 + phase) * HDIM * HDIM;
    #pragma unroll
    for (int i = 0; i < 4; ++i) {
      int flat = i * 256 + t;
      int r = flat >> 4;
      int o = (flat & 15) * 8;
      int row = row0 + r;
      f16x8 v{};
      if (row < N) v = *reinterpret_cast<const f16x8*>(src + (size_t)row * HDIM + o);
      *reinterpret_cast<f16x8*>(&As[r * 136 + o]) = v;
    }
    #pragma unroll
    for (int i = 0; i < 8; ++i) {
      int flat = i * 256 + t;
      int n = flat >> 4;
      int o = (flat & 15) * 8;
      *reinterpret_cast<f16x8*>(&Ws[n * 136 + o]) =
          *reinterpret_cast<const f16x8*>(wp + (size_t)n * HDIM + o);
    }
    __syncthreads();
    #pragma unroll
    for (int s = 0; s < 4; ++s) {
      f16x8 a0 = *reinterpret_cast<const f16x8*>(
          &As[(wr * 32 + ln15) * 136 + s * 32 + quad * 8]);
      f16x8 a1 = *reinterpret_cast<const f16x8*>(
          &As[(wr * 32 + 16 + ln15) * 136 + s * 32 + quad * 8]);
      #pragma unroll
      for (int ni = 0; ni < 4; ++ni) {
        f16x8 bf = *reinterpret_cast<const f16x8*>(
            &Ws[(wc * 64 + ni * 16 + ln15) * 136 + s * 32 + quad * 8]);
        acc[0][ni] = __builtin_amdgcn_mfma_f32_16x16x32_f16(a0, bf, acc[0][ni], 0, 0, 0);
        acc[1][ni] = __builtin_amdgcn_mfma_f32_16x16x32_f16(a1, bf, acc[1][ni], 0, 0, 0);
      }
    }
    __syncthreads();
  }

  #pragma unroll
  for (int ni = 0; ni < 4; ++ni) {
    const int col = wc * 64 + ni * 16 + ln15;
    float bias = b[(group * 2) * HDIM + col];
    if (group < 2) bias += b[(group * 2 + 1) * HDIM + col];
    #pragma unroll
    for (int mi = 0; mi < 2; ++mi) {
      #pragma unroll
      for (int r = 0; r < 4; ++r) {
        int row = row0 + wr * 32 + mi * 16 + quad * 4 + r;
        if (row >= N) continue;
        size_t idx = (size_t)row * HDIM + col;
        float v = acc[mi][ni][r] + bias;
        if (group == 0) {
          zb[idx] = (f16)v;
        } else if (group == 1) {
          float rg = 1.f / (1.f + expf(-v));
          cb[idx] = (f16)(rg * hi[idx]);
        } else {
          hpre[idx] = v;
        }
      }
    }
  }
}

// ================= MFMA final GEMM + GRU combine =================
__global__ __launch_bounds__(256, 3) void gemm_final_kernel(
    const f16* __restrict__ Ctot, const f16* __restrict__ WT5,
    const float* __restrict__ b5, const f16* __restrict__ zb,
    const float* __restrict__ hi, float* __restrict__ outi,
    f16* __restrict__ xb, int N) {
  __shared__ f16 As[64 * 136];
  __shared__ f16 Ws[128 * 136];
  const int t = threadIdx.x;
  const int w = t >> 6, wr = w >> 1, wc = w & 1;
  const int lane = t & 63, ln15 = lane & 15, quad = lane >> 4;
  const int row0 = blockIdx.x * 64;
  f32x4 acc[2][4];
  #pragma unroll
  for (int i = 0; i < 2; ++i)
    #pragma unroll
    for (int j = 0; j < 4; ++j) acc[i][j] = (f32x4){0.f, 0.f, 0.f, 0.f};

  #pragma unroll
  for (int i = 0; i < 4; ++i) {
    int flat = i * 256 + t;
    int r = flat >> 4;
    int o = (flat & 15) * 8;
    int row = row0 + r;
    f16x8 v{};
    if (row < N) v = *reinterpret_cast<const f16x8*>(Ctot + (size_t)row * HDIM + o);
    *reinterpret_cast<f16x8*>(&As[r * 136 + o]) = v;
  }
  #pragma unroll
  for (int i = 0; i < 8; ++i) {
    int flat = i * 256 + t;
    int n = flat >> 4;
    int o = (flat & 15) * 8;
    *reinterpret_cast<f16x8*>(&Ws[n * 136 + o]) =
        *reinterpret_cast<const f16x8*>(WT5 + (size_t)n * HDIM + o);
  }
  __syncthreads();
  #pragma unroll
  for (int s = 0; s < 4; ++s) {
    f16x8 a0 = *reinterpret_cast<const f16x8*>(
        &As[(wr * 32 + ln15) * 136 + s * 32 + quad * 8]);
    f16x8 a1 = *reinterpret_cast<const f16x8*>(
        &As[(wr * 32 + 16 + ln15) * 136 + s * 32 + quad * 8]);
    #pragma unroll
    for (int ni = 0; ni < 4; ++ni) {
      f16x8 bf = *reinterpret_cast<const f16x8*>(
          &Ws[(wc * 64 + ni * 16 + ln15) * 136 + s * 32 + quad * 8]);
      acc[0][ni] = __builtin_amdgcn_mfma_f32_16x16x32_f16(a0, bf, acc[0][ni], 0, 0, 0);
      acc[1][ni] = __builtin_amdgcn_mfma_f32_16x16x32_f16(a1, bf, acc[1][ni], 0, 0, 0);
    }
  }

  #pragma unroll
  for (int ni = 0; ni < 4; ++ni) {
    const int col = wc * 64 + ni * 16 + ln15;
    float bias = b5[col];
    #pragma unroll
    for (int mi = 0; mi < 2; ++mi) {
      #pragma unroll
      for (int r = 0; r < 4; ++r) {
        int row = row0 + wr * 32 + mi * 16 + quad * 4 + r;
        if (row >= N) continue;
        size_t idx = (size_t)row * HDIM + col;
        float v = acc[mi][ni][r] + bias + outi[idx];  // + hpre
        float ht = tanhf(v);
        float z = 1.f / (1.f + expf(-(float)zb[idx]));
        float o = z * hi[idx] + (1.f - z) * ht;
        outi[idx] = o;
        xb[idx] = (f16)o;
      }
    }
  }
}

extern "C" void kernel_launch(void* const* d_in, const int* in_sizes, int n_in,
                              void* d_out, int out_size, void* d_ws, size_t ws_size,
                              hipStream_t stream) {
  const float* inp = (const float*)d_in[0];
  const int*   edg = (const int*)d_in[1];
  const float* h   = (const float*)d_in[2];
  const float* W   = (const float*)d_in[3];
  const float* b   = (const float*)d_in[4];
  float* out = (float*)d_out;

  const int NH = in_sizes[0];      // N*H
  const int N  = NH / HDIM;
  const int E  = in_sizes[1] / 2;
  const int L  = in_sizes[2] / NH;

  f16* Af   = (f16*)d_ws;               // A aggregate / Ctot (reused)
  f16* Bhf  = Af + (size_t)NH;          // Bh aggregate
  f16* zbuf = Bhf + (size_t)NH;         // zpre
  f16* cbuf = zbuf + (size_t)NH;        // r*h
  f16* xbuf = cbuf + (size_t)NH;        // x f16
  f16* hbuf = xbuf + (size_t)NH;        // h_i f16
  f16* WT   = hbuf + (size_t)NH;        // L*6*H*H transposed f16 weights
  int* deg     = (int*)(WT + (size_t)L * 6 * HDIM * HDIM);
  int* offs    = deg + N;               // N+1
  int* bsum    = offs + (N + 1);        // 256
  int* boff    = bsum + 256;            // 256
  u16* rank    = (u16*)(boff + 256);    // E
  u16* csr_src = rank + (size_t)E;      // E

  const int eblocks = (E + 255) / 256;
  const int fblocks = (E + 1023) / 1024;
  const int nodeblocks = (N + 3) / 4;
  const int sblocks = (N + 63) / 64;
  const int n4 = NH / 4;
  const int cvblocks = (n4 + 255) / 256;
  const int rowblocks = (N + 63) / 64;
  const int chunk = (N + 255) / 256;    // <=256 requires N<=65536

  // ---- one-time per call: CSR build, weight transpose, input f16 ----
  hipMemsetAsync(deg, 0, (size_t)N * sizeof(int), stream);
  hipLaunchKernelGGL(degrank_kernel, dim3(eblocks), dim3(256), 0, stream,
                     edg, deg, rank, E);
  hipLaunchKernelGGL(scan_part_kernel, dim3(256), dim3(256), 0, stream,
                     deg, bsum, N, chunk);
  hipLaunchKernelGGL(scan_top_kernel, dim3(1), dim3(256), 0, stream,
                     bsum, boff, offs, N);
  hipLaunchKernelGGL(scan_fin_kernel, dim3(256), dim3(256), 0, stream,
                     deg, boff, offs, N, chunk);
  hipLaunchKernelGGL(fill_kernel, dim3(fblocks), dim3(256), 0, stream,
                     edg, offs, rank, csr_src, E);
  hipLaunchKernelGGL(sort_kernel, dim3(sblocks), dim3(64), 0, stream,
                     offs, csr_src, N);
  hipLaunchKernelGGL(transw_kernel, dim3(16, L * 6), dim3(256), 0, stream,
                     W, WT);
  hipLaunchKernelGGL(convh_kernel, dim3(cvblocks), dim3(256), 0, stream,
                     inp, xbuf, n4);

  for (int i = 0; i < L; ++i) {
    const float* hi = h + (size_t)i * NH;
    const f16* WTi = WT + (size_t)i * 6 * HDIM * HDIM;
    const float* bi = b + (size_t)i * 6 * HDIM;
    float* outi = out + (size_t)i * NH;

    hipLaunchKernelGGL(convh_kernel, dim3(cvblocks), dim3(256), 0, stream,
                       hi, hbuf, n4);
    hipLaunchKernelGGL(pull2_kernel, dim3(nodeblocks), dim3(256), 0, stream,
                       csr_src, offs, xbuf, hbuf, Af, Bhf, N);
    hipLaunchKernelGGL(gemm3_kernel, dim3(rowblocks, 3), dim3(256), 0, stream,
                       Af, Bhf, WTi, bi, hi, zbuf, cbuf, outi, N);
    hipLaunchKernelGGL(pull1_kernel, dim3(nodeblocks), dim3(256), 0, stream,
                       csr_src, offs, cbuf, Af, N);   // Af reused as Ctot
    hipLaunchKernelGGL(gemm_final_kernel, dim3(rowblocks), dim3(256), 0, stream,
                       Af, WTi + (size_t)5 * HDIM * HDIM, bi + 5 * HDIM,
                       zbuf, hi, outi, xbuf, N);
  }
}

// Round 2
// 750.558 us; speedup vs baseline: 1.1524x; 1.1524x over previous
//
#include <hip/hip_runtime.h>
#include <math.h>

#define HDIM 128

typedef _Float16 f16;
typedef unsigned short u16;
typedef __attribute__((ext_vector_type(2))) _Float16 f16x2;
typedef __attribute__((ext_vector_type(4))) _Float16 f16x4;
typedef __attribute__((ext_vector_type(8))) _Float16 f16x8;
typedef __attribute__((ext_vector_type(4))) float f32x4;

// ================= CSR build =================
// bucket-rank: counts per (dst, src>>12) AND records each edge's rank within
// its (dst,bucket). Folding the 16 src-buckets in ascending order at fill time
// yields a CSR approximately sorted by src within each dst bucket -> concurrent
// waves walk srcs in ascending order -> gather working set fits per-XCD L2.
__global__ __launch_bounds__(256) void degrank_kernel(
    const int* __restrict__ edg, int* __restrict__ cnt,
    u16* __restrict__ rank, int E) {
  int e = blockIdx.x * 256 + threadIdx.x;
  if (e < E) {
    int src = edg[e];
    int dst = edg[E + e];
    rank[e] = (u16)atomicAdd(&cnt[dst * 16 + (src >> 12)], 1);
  }
}

// per-node: exclusive-scan the 16 bucket counters in place, emit total degree
__global__ __launch_bounds__(256) void nodescan_kernel(
    int* __restrict__ cnt, int* __restrict__ deg, int N) {
  int node = blockIdx.x * 256 + threadIdx.x;
  if (node >= N) return;
  int* c = cnt + node * 16;
  int s = 0;
  #pragma unroll
  for (int b = 0; b < 16; ++b) {
    int v = c[b];
    c[b] = s;
    s += v;
  }
  deg[node] = s;
}

__global__ __launch_bounds__(256) void scan_part_kernel(
    const int* __restrict__ deg, int* __restrict__ bsum, int n, int chunk) {
  __shared__ int red[256];
  const int b = blockIdx.x, t = threadIdx.x;
  const int begin = b * chunk;
  const int end = min(begin + chunk, n);
  int s = 0;
  for (int i = begin + t; i < end; i += 256) s += deg[i];
  red[t] = s;
  __syncthreads();
  for (int off = 128; off > 0; off >>= 1) {
    if (t < off) red[t] += red[t + off];
    __syncthreads();
  }
  if (t == 0) bsum[b] = red[0];
}

__global__ __launch_bounds__(256) void scan_top_kernel(
    const int* __restrict__ bsum, int* __restrict__ boff,
    int* __restrict__ offs, int n) {
  __shared__ int sh[256];
  const int t = threadIdx.x;
  int v = bsum[t];
  sh[t] = v;
  __syncthreads();
  for (int off = 1; off < 256; off <<= 1) {
    int add = (t >= off) ? sh[t - off] : 0;
    __syncthreads();
    sh[t] += add;
    __syncthreads();
  }
  boff[t] = sh[t] - v;
  if (t == 255) offs[n] = sh[255];
}

__global__ __launch_bounds__(256) void scan_fin_kernel(
    const int* __restrict__ deg, const int* __restrict__ boff,
    int* __restrict__ offs, int n, int chunk) {
  __shared__ int sh[256];
  const int b = blockIdx.x, t = threadIdx.x;
  const int idx = b * chunk + t;
  int v = (t < chunk && idx < n) ? deg[idx] : 0;
  sh[t] = v;
  __syncthreads();
  for (int off = 1; off < 256; off <<= 1) {
    int add = (t >= off) ? sh[t - off] : 0;
    __syncthreads();
    sh[t] += add;
    __syncthreads();
  }
  if (t < chunk && idx < n) offs[idx] = boff[b] + sh[t] - v;
}

// atomic-free fill: pos = offs[dst] + bucket_off[dst][src>>12] + rank[e]
__global__ __launch_bounds__(256) void fill_kernel(
    const int* __restrict__ edg, const int* __restrict__ offs,
    const int* __restrict__ cnt, const u16* __restrict__ rank,
    u16* __restrict__ csr_src, int E) {
  int i = blockIdx.x * 256 + threadIdx.x;
  int e0 = i * 4;
  if (e0 >= E) return;
  if (e0 + 4 <= E) {
    int4 s4 = *reinterpret_cast<const int4*>(edg + e0);
    int4 d4 = *reinterpret_cast<const int4*>(edg + E + e0);
    ushort4 r4 = *reinterpret_cast<const ushort4*>(rank + e0);
    csr_src[offs[d4.x] + cnt[d4.x * 16 + (s4.x >> 12)] + r4.x] = (u16)s4.x;
    csr_src[offs[d4.y] + cnt[d4.y * 16 + (s4.y >> 12)] + r4.y] = (u16)s4.y;
    csr_src[offs[d4.z] + cnt[d4.z * 16 + (s4.z >> 12)] + r4.z] = (u16)s4.z;
    csr_src[offs[d4.w] + cnt[d4.w * 16 + (s4.w >> 12)] + r4.w] = (u16)s4.w;
  } else {
    for (int e = e0; e < E; ++e) {
      int src = edg[e];
      int dst = edg[E + e];
      csr_src[offs[dst] + cnt[dst * 16 + (src >> 12)] + rank[e]] = (u16)src;
    }
  }
}

// ================= fp32 -> fp16 conversion =================
__global__ __launch_bounds__(256) void convh_kernel(
    const float* __restrict__ s, f16* __restrict__ d, int n4) {
  int i = blockIdx.x * 256 + threadIdx.x;
  if (i < n4) {
    float4 v = reinterpret_cast<const float4*>(s)[i];
    f16x4 o;
    o[0] = (f16)v.x; o[1] = (f16)v.y; o[2] = (f16)v.z; o[3] = (f16)v.w;
    reinterpret_cast<f16x4*>(d)[i] = o;
  }
}

// ================= W transpose + fp16: WT[gate][n][k] =================
__global__ __launch_bounds__(256) void transw_kernel(
    const float* __restrict__ W, f16* __restrict__ WT) {
  __shared__ float sh[32][33];
  const int g = blockIdx.y;
  const int ti = blockIdx.x >> 2;
  const int tj = blockIdx.x & 3;
  const float* __restrict__ wp = W + (size_t)g * HDIM * HDIM;
  f16* __restrict__ op = WT + (size_t)g * HDIM * HDIM;
  const int t = threadIdx.x;
  #pragma unroll
  for (int it = 0; it < 4; ++it) {
    int elem = it * 256 + t;
    int r = elem >> 5, c = elem & 31;
    sh[r][c] = wp[(size_t)(ti * 32 + r) * HDIM + tj * 32 + c];
  }
  __syncthreads();
  #pragma unroll
  for (int it = 0; it < 4; ++it) {
    int elem = it * 256 + t;
    int cc = elem >> 5, rr = elem & 31;
    op[(size_t)(tj * 32 + cc) * HDIM + ti * 32 + rr] = (f16)sh[rr][cc];
  }
}

// ================= pull aggregation =================
// wave = 1 node. lanes split: half (lane>>5) picks table {x,h}; within a half,
// sub=(lane>>4)&1 picks edge parity; 16 lanes x f16x8 = one 256B row.
__global__ __launch_bounds__(256) void pull2_kernel(
    const u16* __restrict__ csr_src, const int* __restrict__ offs,
    const f16* __restrict__ xb, const f16* __restrict__ hb,
    f16* __restrict__ A, f16* __restrict__ Bh, int N) {
  const int node = blockIdx.x * 4 + (threadIdx.x >> 6);
  if (node >= N) return;
  const int lane = threadIdx.x & 63;
  const int half = lane >> 5;
  const int sub = (lane >> 4) & 1;
  const int c = (lane & 15) << 3;
  const f16* __restrict__ nb = half ? hb : xb;
  f16* __restrict__ dst = half ? Bh : A;
  const int s = offs[node];
  const int e = offs[node + 1];
  float acc[8];
  if (sub == 0) {
    f16x8 sv = *reinterpret_cast<const f16x8*>(nb + (size_t)node * HDIM + c);
    #pragma unroll
    for (int q = 0; q < 8; ++q) acc[q] = (float)sv[q];
  } else {
    #pragma unroll
    for (int q = 0; q < 8; ++q) acc[q] = 0.f;
  }
  int k = s;
  for (; k + 8 <= e; k += 8) {
    int j0 = csr_src[k + sub];
    int j1 = csr_src[k + 2 + sub];
    int j2 = csr_src[k + 4 + sub];
    int j3 = csr_src[k + 6 + sub];
    f16x8 u0 = *reinterpret_cast<const f16x8*>(nb + (size_t)j0 * HDIM + c);
    f16x8 u1 = *reinterpret_cast<const f16x8*>(nb + (size_t)j1 * HDIM + c);
    f16x8 u2 = *reinterpret_cast<const f16x8*>(nb + (size_t)j2 * HDIM + c);
    f16x8 u3 = *reinterpret_cast<const f16x8*>(nb + (size_t)j3 * HDIM + c);
    #pragma unroll
    for (int q = 0; q < 8; ++q)
      acc[q] += ((float)u0[q] + (float)u1[q]) + ((float)u2[q] + (float)u3[q]);
  }
  for (; k < e; k += 2) {
    int j = k + sub;
    if (j < e) {
      f16x8 u = *reinterpret_cast<const f16x8*>(nb + (size_t)csr_src[j] * HDIM + c);
      #pragma unroll
      for (int q = 0; q < 8; ++q) acc[q] += (float)u[q];
    }
  }
  #pragma unroll
  for (int q = 0; q < 8; ++q) acc[q] += __shfl_xor(acc[q], 16, 64);
  if (sub == 0) {
    f16x8 o;
    #pragma unroll
    for (int q = 0; q < 8; ++q) o[q] = (f16)acc[q];
    *reinterpret_cast<f16x8*>(dst + (size_t)node * HDIM + c) = o;
  }
}

// wave = 1 node, 4 edge-slots (sub=lane>>4), f16x8 per lane.
__global__ __launch_bounds__(256) void pull1_kernel(
    const u16* __restrict__ csr_src, const int* __restrict__ offs,
    const f16* __restrict__ cb, f16* __restrict__ Ctot, int N) {
  const int node = blockIdx.x * 4 + (threadIdx.x >> 6);
  if (node >= N) return;
  const int lane = threadIdx.x & 63;
  const int sub = lane >> 4;
  const int c = (lane & 15) << 3;
  const int s = offs[node];
  const int e = offs[node + 1];
  float acc[8];
  if (sub == 0) {
    f16x8 sv = *reinterpret_cast<const f16x8*>(cb + (size_t)node * HDIM + c);
    #pragma unroll
    for (int q = 0; q < 8; ++q) acc[q] = (float)sv[q];
  } else {
    #pragma unroll
    for (int q = 0; q < 8; ++q) acc[q] = 0.f;
  }
  int k = s;
  for (; k + 8 <= e; k += 8) {
    int j0 = csr_src[k + sub];
    int j1 = csr_src[k + 4 + sub];
    f16x8 u0 = *reinterpret_cast<const f16x8*>(cb + (size_t)j0 * HDIM + c);
    f16x8 u1 = *reinterpret_cast<const f16x8*>(cb + (size_t)j1 * HDIM + c);
    #pragma unroll
    for (int q = 0; q < 8; ++q) acc[q] += (float)u0[q] + (float)u1[q];
  }
  for (; k < e; k += 4) {
    int j = k + sub;
    if (j < e) {
      f16x8 u = *reinterpret_cast<const f16x8*>(cb + (size_t)csr_src[j] * HDIM + c);
      #pragma unroll
      for (int q = 0; q < 8; ++q) acc[q] += (float)u[q];
    }
  }
  #pragma unroll
  for (int q = 0; q < 8; ++q) {
    acc[q] += __shfl_xor(acc[q], 16, 64);
    acc[q] += __shfl_xor(acc[q], 32, 64);
  }
  if (sub == 0) {
    f16x8 o;
    #pragma unroll
    for (int q = 0; q < 8; ++q) o[q] = (f16)acc[q];
    *reinterpret_cast<f16x8*>(Ctot + (size_t)node * HDIM + c) = o;
  }
}

// ================= MFMA gate GEMM =================
__global__ __launch_bounds__(256, 3) void gemm3_kernel(
    const f16* __restrict__ A, const f16* __restrict__ Bh,
    const f16* __restrict__ WT, const float* __restrict__ b,
    const float* __restrict__ hi, f16* __restrict__ zb,
    f16* __restrict__ cb, float* __restrict__ hpre, int N) {
  __shared__ f16 As[64 * 136];
  __shared__ f16 Ws[128 * 136];
  const int t = threadIdx.x;
  const int w = t >> 6, wr = w >> 1, wc = w & 1;
  const int lane = t & 63, ln15 = lane & 15, quad = lane >> 4;
  const int row0 = blockIdx.x * 64;
  const int group = blockIdx.y;
  f32x4 acc[2][4];
  #pragma unroll
  for (int i = 0; i < 2; ++i)
    #pragma unroll
    for (int j = 0; j < 4; ++j) acc[i][j] = (f32x4){0.f, 0.f, 0.f, 0.f};

  const int nphase = (group < 2) ? 2 : 1;
  for (int phase = 0; phase < nphase; ++phase) {
    const f16* __restrict__ src = phase ? Bh : A;
    const f16* __restrict__ wp = WT + (size_t)(group * 2 + phase) * HDIM * HDIM;
    #pragma unroll
    for (int i = 0; i < 4; ++i) {
      int flat = i * 256 + t;
      int r = flat >> 4;
      int o = (flat & 15) * 8;
      int row = row0 + r;
      f16x8 v{};
      if (row < N) v = *reinterpret_cast<const f16x8*>(src + (size_t)row * HDIM + o);
      *reinterpret_cast<f16x8*>(&As[r * 136 + o]) = v;
    }
    #pragma unroll
    for (int i = 0; i < 8; ++i) {
      int flat = i * 256 + t;
      int n = flat >> 4;
      int o = (flat & 15) * 8;
      *reinterpret_cast<f16x8*>(&Ws[n * 136 + o]) =
          *reinterpret_cast<const f16x8*>(wp + (size_t)n * HDIM + o);
    }
    __syncthreads();
    #pragma unroll
    for (int s = 0; s < 4; ++s) {
      f16x8 a0 = *reinterpret_cast<const f16x8*>(
          &As[(wr * 32 + ln15) * 136 + s * 32 + quad * 8]);
      f16x8 a1 = *reinterpret_cast<const f16x8*>(
          &As[(wr * 32 + 16 + ln15) * 136 + s * 32 + quad * 8]);
      #pragma unroll
      for (int ni = 0; ni < 4; ++ni) {
        f16x8 bf = *reinterpret_cast<const f16x8*>(
            &Ws[(wc * 64 + ni * 16 + ln15) * 136 + s * 32 + quad * 8]);
        acc[0][ni] = __builtin_amdgcn_mfma_f32_16x16x32_f16(a0, bf, acc[0][ni], 0, 0, 0);
        acc[1][ni] = __builtin_amdgcn_mfma_f32_16x16x32_f16(a1, bf, acc[1][ni], 0, 0, 0);
      }
    }
    __syncthreads();
  }

  #pragma unroll
  for (int ni = 0; ni < 4; ++ni) {
    const int col = wc * 64 + ni * 16 + ln15;
    float bias = b[(group * 2) * HDIM + col];
    if (group < 2) bias += b[(group * 2 + 1) * HDIM + col];
    #pragma unroll
    for (int mi = 0; mi < 2; ++mi) {
      #pragma unroll
      for (int r = 0; r < 4; ++r) {
        int row = row0 + wr * 32 + mi * 16 + quad * 4 + r;
        if (row >= N) continue;
        size_t idx = (size_t)row * HDIM + col;
        float v = acc[mi][ni][r] + bias;
        if (group == 0) {
          zb[idx] = (f16)v;
        } else if (group == 1) {
          float rg = 1.f / (1.f + expf(-v));
          cb[idx] = (f16)(rg * hi[idx]);
        } else {
          hpre[idx] = v;
        }
      }
    }
  }
}

// ================= MFMA final GEMM + GRU combine =================
__global__ __launch_bounds__(256, 3) void gemm_final_kernel(
    const f16* __restrict__ Ctot, const f16* __restrict__ WT5,
    const float* __restrict__ b5, const f16* __restrict__ zb,
    const float* __restrict__ hi, float* __restrict__ outi,
    f16* __restrict__ xb, int N) {
  __shared__ f16 As[64 * 136];
  __shared__ f16 Ws[128 * 136];
  const int t = threadIdx.x;
  const int w = t >> 6, wr = w >> 1, wc = w & 1;
  const int lane = t & 63, ln15 = lane & 15, quad = lane >> 4;
  const int row0 = blockIdx.x * 64;
  f32x4 acc[2][4];
  #pragma unroll
  for (int i = 0; i < 2; ++i)
    #pragma unroll
    for (int j = 0; j < 4; ++j) acc[i][j] = (f32x4){0.f, 0.f, 0.f, 0.f};

  #pragma unroll
  for (int i = 0; i < 4; ++i) {
    int flat = i * 256 + t;
    int r = flat >> 4;
    int o = (flat & 15) * 8;
    int row = row0 + r;
    f16x8 v{};
    if (row < N) v = *reinterpret_cast<const f16x8*>(Ctot + (size_t)row * HDIM + o);
    *reinterpret_cast<f16x8*>(&As[r * 136 + o]) = v;
  }
  #pragma unroll
  for (int i = 0; i < 8; ++i) {
    int flat = i * 256 + t;
    int n = flat >> 4;
    int o = (flat & 15) * 8;
    *reinterpret_cast<f16x8*>(&Ws[n * 136 + o]) =
        *reinterpret_cast<const f16x8*>(WT5 + (size_t)n * HDIM + o);
  }
  __syncthreads();
  #pragma unroll
  for (int s = 0; s < 4; ++s) {
    f16x8 a0 = *reinterpret_cast<const f16x8*>(
        &As[(wr * 32 + ln15) * 136 + s * 32 + quad * 8]);
    f16x8 a1 = *reinterpret_cast<const f16x8*>(
        &As[(wr * 32 + 16 + ln15) * 136 + s * 32 + quad * 8]);
    #pragma unroll
    for (int ni = 0; ni < 4; ++ni) {
      f16x8 bf = *reinterpret_cast<const f16x8*>(
          &Ws[(wc * 64 + ni * 16 + ln15) * 136 + s * 32 + quad * 8]);
      acc[0][ni] = __builtin_amdgcn_mfma_f32_16x16x32_f16(a0, bf, acc[0][ni], 0, 0, 0);
      acc[1][ni] = __builtin_amdgcn_mfma_f32_16x16x32_f16(a1, bf, acc[1][ni], 0, 0, 0);
    }
  }

  #pragma unroll
  for (int ni = 0; ni < 4; ++ni) {
    const int col = wc * 64 + ni * 16 + ln15;
    float bias = b5[col];
    #pragma unroll
    for (int mi = 0; mi < 2; ++mi) {
      #pragma unroll
      for (int r = 0; r < 4; ++r) {
        int row = row0 + wr * 32 + mi * 16 + quad * 4 + r;
        if (row >= N) continue;
        size_t idx = (size_t)row * HDIM + col;
        float v = acc[mi][ni][r] + bias + outi[idx];  // + hpre
        float ht = tanhf(v);
        float z = 1.f / (1.f + expf(-(float)zb[idx]));
        float o = z * hi[idx] + (1.f - z) * ht;
        outi[idx] = o;
        xb[idx] = (f16)o;
      }
    }
  }
}

extern "C" void kernel_launch(void* const* d_in, const int* in_sizes, int n_in,
                              void* d_out, int out_size, void* d_ws, size_t ws_size,
                              hipStream_t stream) {
  const float* inp = (const float*)d_in[0];
  const int*   edg = (const int*)d_in[1];
  const float* h   = (const float*)d_in[2];
  const float* W   = (const float*)d_in[3];
  const float* b   = (const float*)d_in[4];
  float* out = (float*)d_out;

  const int NH = in_sizes[0];      // N*H
  const int N  = NH / HDIM;
  const int E  = in_sizes[1] / 2;
  const int L  = in_sizes[2] / NH;

  f16* Af   = (f16*)d_ws;               // A aggregate / Ctot (reused)
  f16* Bhf  = Af + (size_t)NH;          // Bh aggregate
  f16* zbuf = Bhf + (size_t)NH;         // zpre
  f16* cbuf = zbuf + (size_t)NH;        // r*h
  f16* xbuf = cbuf + (size_t)NH;        // x f16
  f16* hbuf = xbuf + (size_t)NH;        // h_i f16
  f16* WT   = hbuf + (size_t)NH;        // L*6*H*H transposed f16 weights
  int* deg     = (int*)(WT + (size_t)L * 6 * HDIM * HDIM);
  int* offs    = deg + N;               // N+1
  int* bsum    = offs + (N + 1);        // 256
  int* boff    = bsum + 256;            // 256
  u16* rank    = (u16*)(boff + 256);    // E
  u16* csr_src = rank + (size_t)E;      // E
  // bucket counters: N*16 ints, only live during CSR build -> overlay on Af
  // (Af region = NH f16 = N*256 bytes >= N*64 bytes needed)
  int* cnt     = (int*)Af;

  const int eblocks = (E + 255) / 256;
  const int fblocks = (E + 1023) / 1024;
  const int nodeblocks = (N + 3) / 4;
  const int nsblocks = (N + 255) / 256;
  const int n4 = NH / 4;
  const int cvblocks = (n4 + 255) / 256;
  const int rowblocks = (N + 63) / 64;
  const int chunk = (N + 255) / 256;    // <=256 requires N<=65536

  // ---- one-time per call: CSR build (approx src-sorted), transpose, f16 ----
  hipMemsetAsync(cnt, 0, (size_t)N * 16 * sizeof(int), stream);
  hipLaunchKernelGGL(degrank_kernel, dim3(eblocks), dim3(256), 0, stream,
                     edg, cnt, rank, E);
  hipLaunchKernelGGL(nodescan_kernel, dim3(nsblocks), dim3(256), 0, stream,
                     cnt, deg, N);
  hipLaunchKernelGGL(scan_part_kernel, dim3(256), dim3(256), 0, stream,
                     deg, bsum, N, chunk);
  hipLaunchKernelGGL(scan_top_kernel, dim3(1), dim3(256), 0, stream,
                     bsum, boff, offs, N);
  hipLaunchKernelGGL(scan_fin_kernel, dim3(256), dim3(256), 0, stream,
                     deg, boff, offs, N, chunk);
  hipLaunchKernelGGL(fill_kernel, dim3(fblocks), dim3(256), 0, stream,
                     edg, offs, cnt, rank, csr_src, E);
  hipLaunchKernelGGL(transw_kernel, dim3(16, L * 6), dim3(256), 0, stream,
                     W, WT);
  hipLaunchKernelGGL(convh_kernel, dim3(cvblocks), dim3(256), 0, stream,
                     inp, xbuf, n4);

  for (int i = 0; i < L; ++i) {
    const float* hi = h + (size_t)i * NH;
    const f16* WTi = WT + (size_t)i * 6 * HDIM * HDIM;
    const float* bi = b + (size_t)i * 6 * HDIM;
    float* outi = out + (size_t)i * NH;

    hipLaunchKernelGGL(convh_kernel, dim3(cvblocks), dim3(256), 0, stream,
                       hi, hbuf, n4);
    hipLaunchKernelGGL(pull2_kernel, dim3(nodeblocks), dim3(256), 0, stream,
                       csr_src, offs, xbuf, hbuf, Af, Bhf, N);
    hipLaunchKernelGGL(gemm3_kernel, dim3(rowblocks, 3), dim3(256), 0, stream,
                       Af, Bhf, WTi, bi, hi, zbuf, cbuf, outi, N);
    hipLaunchKernelGGL(pull1_kernel, dim3(nodeblocks), dim3(256), 0, stream,
                       csr_src, offs, cbuf, Af, N);   // Af reused as Ctot
    hipLaunchKernelGGL(gemm_final_kernel, dim3(rowblocks), dim3(256), 0, stream,
                       Af, WTi + (size_t)5 * HDIM * HDIM, bi + 5 * HDIM,
                       zbuf, hi, outi, xbuf, N);
  }
}

// Round 3
// 749.428 us; speedup vs baseline: 1.1542x; 1.0015x over previous
//
#include <hip/hip_runtime.h>
#include <math.h>

#define HDIM 128

typedef _Float16 f16;
typedef unsigned short u16;
typedef __attribute__((ext_vector_type(2))) _Float16 f16x2;
typedef __attribute__((ext_vector_type(4))) _Float16 f16x4;
typedef __attribute__((ext_vector_type(8))) _Float16 f16x8;
typedef __attribute__((ext_vector_type(4))) float f32x4;

// ================= CSR build =================
// bucket-rank: counts per (dst, src>>12); folding buckets ascending at fill
// time yields approx src-sorted lists (kept: free, small fetch win).
__global__ __launch_bounds__(256) void degrank_kernel(
    const int* __restrict__ edg, int* __restrict__ cnt,
    u16* __restrict__ rank, int E) {
  int e = blockIdx.x * 256 + threadIdx.x;
  if (e < E) {
    int src = edg[e];
    int dst = edg[E + e];
    rank[e] = (u16)atomicAdd(&cnt[dst * 16 + (src >> 12)], 1);
  }
}

// per-node: exclusive-scan the 16 bucket counters in place, emit total degree
__global__ __launch_bounds__(256) void nodescan_kernel(
    int* __restrict__ cnt, int* __restrict__ deg, int N) {
  int node = blockIdx.x * 256 + threadIdx.x;
  if (node >= N) return;
  int* c = cnt + node * 16;
  int s = 0;
  #pragma unroll
  for (int b = 0; b < 16; ++b) {
    int v = c[b];
    c[b] = s;
    s += v;
  }
  deg[node] = s;
}

__global__ __launch_bounds__(256) void scan_part_kernel(
    const int* __restrict__ deg, int* __restrict__ bsum, int n, int chunk) {
  __shared__ int red[256];
  const int b = blockIdx.x, t = threadIdx.x;
  const int begin = b * chunk;
  const int end = min(begin + chunk, n);
  int s = 0;
  for (int i = begin + t; i < end; i += 256) s += deg[i];
  red[t] = s;
  __syncthreads();
  for (int off = 128; off > 0; off >>= 1) {
    if (t < off) red[t] += red[t + off];
    __syncthreads();
  }
  if (t == 0) bsum[b] = red[0];
}

__global__ __launch_bounds__(256) void scan_top_kernel(
    const int* __restrict__ bsum, int* __restrict__ boff,
    int* __restrict__ offs, int n) {
  __shared__ int sh[256];
  const int t = threadIdx.x;
  int v = bsum[t];
  sh[t] = v;
  __syncthreads();
  for (int off = 1; off < 256; off <<= 1) {
    int add = (t >= off) ? sh[t - off] : 0;
    __syncthreads();
    sh[t] += add;
    __syncthreads();
  }
  boff[t] = sh[t] - v;
  if (t == 255) offs[n] = sh[255];
}

__global__ __launch_bounds__(256) void scan_fin_kernel(
    const int* __restrict__ deg, const int* __restrict__ boff,
    int* __restrict__ offs, int n, int chunk) {
  __shared__ int sh[256];
  const int b = blockIdx.x, t = threadIdx.x;
  const int idx = b * chunk + t;
  int v = (t < chunk && idx < n) ? deg[idx] : 0;
  sh[t] = v;
  __syncthreads();
  for (int off = 1; off < 256; off <<= 1) {
    int add = (t >= off) ? sh[t - off] : 0;
    __syncthreads();
    sh[t] += add;
    __syncthreads();
  }
  if (t < chunk && idx < n) offs[idx] = boff[b] + sh[t] - v;
}

// atomic-free fill: pos = offs[dst] + bucket_off[dst][src>>12] + rank[e]
__global__ __launch_bounds__(256) void fill_kernel(
    const int* __restrict__ edg, const int* __restrict__ offs,
    const int* __restrict__ cnt, const u16* __restrict__ rank,
    u16* __restrict__ csr_src, int E) {
  int i = blockIdx.x * 256 + threadIdx.x;
  int e0 = i * 4;
  if (e0 >= E) return;
  if (e0 + 4 <= E) {
    int4 s4 = *reinterpret_cast<const int4*>(edg + e0);
    int4 d4 = *reinterpret_cast<const int4*>(edg + E + e0);
    ushort4 r4 = *reinterpret_cast<const ushort4*>(rank + e0);
    csr_src[offs[d4.x] + cnt[d4.x * 16 + (s4.x >> 12)] + r4.x] = (u16)s4.x;
    csr_src[offs[d4.y] + cnt[d4.y * 16 + (s4.y >> 12)] + r4.y] = (u16)s4.y;
    csr_src[offs[d4.z] + cnt[d4.z * 16 + (s4.z >> 12)] + r4.z] = (u16)s4.z;
    csr_src[offs[d4.w] + cnt[d4.w * 16 + (s4.w >> 12)] + r4.w] = (u16)s4.w;
  } else {
    for (int e = e0; e < E; ++e) {
      int src = edg[e];
      int dst = edg[E + e];
      csr_src[offs[dst] + cnt[dst * 16 + (src >> 12)] + rank[e]] = (u16)src;
    }
  }
}

// ================= fp32 -> fp16 conversion =================
__global__ __launch_bounds__(256) void convh_kernel(
    const float* __restrict__ s, f16* __restrict__ d, int n4) {
  int i = blockIdx.x * 256 + threadIdx.x;
  if (i < n4) {
    float4 v = reinterpret_cast<const float4*>(s)[i];
    f16x4 o;
    o[0] = (f16)v.x; o[1] = (f16)v.y; o[2] = (f16)v.z; o[3] = (f16)v.w;
    __builtin_nontemporal_store(o, reinterpret_cast<f16x4*>(d) + i);
  }
}

// ================= W transpose + fp16: WT[gate][n][k] =================
__global__ __launch_bounds__(256) void transw_kernel(
    const float* __restrict__ W, f16* __restrict__ WT) {
  __shared__ float sh[32][33];
  const int g = blockIdx.y;
  const int ti = blockIdx.x >> 2;
  const int tj = blockIdx.x & 3;
  const float* __restrict__ wp = W + (size_t)g * HDIM * HDIM;
  f16* __restrict__ op = WT + (size_t)g * HDIM * HDIM;
  const int t = threadIdx.x;
  #pragma unroll
  for (int it = 0; it < 4; ++it) {
    int elem = it * 256 + t;
    int r = elem >> 5, c = elem & 31;
    sh[r][c] = wp[(size_t)(ti * 32 + r) * HDIM + tj * 32 + c];
  }
  __syncthreads();
  #pragma unroll
  for (int it = 0; it < 4; ++it) {
    int elem = it * 256 + t;
    int cc = elem >> 5, rr = elem & 31;
    op[(size_t)(tj * 32 + cc) * HDIM + ti * 32 + rr] = (f16)sh[rr][cc];
  }
}

// ================= pull aggregation =================
// wave = 1 node. lanes split: half (lane>>5) picks table {x,h}; within a half,
// sub=(lane>>4)&1 picks edge parity; 16 lanes x f16x8 = one 256B row.
// Main loop: 16 edges/iter -> 8 rows in flight per lane-group.
__global__ __launch_bounds__(256) void pull2_kernel(
    const u16* __restrict__ csr_src, const int* __restrict__ offs,
    const f16* __restrict__ xb, const f16* __restrict__ hb,
    f16* __restrict__ A, f16* __restrict__ Bh, int N) {
  const int node = blockIdx.x * 4 + (threadIdx.x >> 6);
  if (node >= N) return;
  const int lane = threadIdx.x & 63;
  const int half = lane >> 5;
  const int sub = (lane >> 4) & 1;
  const int c = (lane & 15) << 3;
  const f16* __restrict__ nb = half ? hb : xb;
  f16* __restrict__ dst = half ? Bh : A;
  const int s = offs[node];
  const int e = offs[node + 1];
  float acc[8];
  if (sub == 0) {
    f16x8 sv = *reinterpret_cast<const f16x8*>(nb + (size_t)node * HDIM + c);
    #pragma unroll
    for (int q = 0; q < 8; ++q) acc[q] = (float)sv[q];
  } else {
    #pragma unroll
    for (int q = 0; q < 8; ++q) acc[q] = 0.f;
  }
  int k = s;
  for (; k + 16 <= e; k += 16) {
    int j0 = csr_src[k + sub];
    int j1 = csr_src[k + 2 + sub];
    int j2 = csr_src[k + 4 + sub];
    int j3 = csr_src[k + 6 + sub];
    int j4 = csr_src[k + 8 + sub];
    int j5 = csr_src[k + 10 + sub];
    int j6 = csr_src[k + 12 + sub];
    int j7 = csr_src[k + 14 + sub];
    f16x8 u0 = *reinterpret_cast<const f16x8*>(nb + (size_t)j0 * HDIM + c);
    f16x8 u1 = *reinterpret_cast<const f16x8*>(nb + (size_t)j1 * HDIM + c);
    f16x8 u2 = *reinterpret_cast<const f16x8*>(nb + (size_t)j2 * HDIM + c);
    f16x8 u3 = *reinterpret_cast<const f16x8*>(nb + (size_t)j3 * HDIM + c);
    f16x8 u4 = *reinterpret_cast<const f16x8*>(nb + (size_t)j4 * HDIM + c);
    f16x8 u5 = *reinterpret_cast<const f16x8*>(nb + (size_t)j5 * HDIM + c);
    f16x8 u6 = *reinterpret_cast<const f16x8*>(nb + (size_t)j6 * HDIM + c);
    f16x8 u7 = *reinterpret_cast<const f16x8*>(nb + (size_t)j7 * HDIM + c);
    #pragma unroll
    for (int q = 0; q < 8; ++q)
      acc[q] += (((float)u0[q] + (float)u1[q]) + ((float)u2[q] + (float)u3[q])) +
                (((float)u4[q] + (float)u5[q]) + ((float)u6[q] + (float)u7[q]));
  }
  for (; k + 8 <= e; k += 8) {
    int j0 = csr_src[k + sub];
    int j1 = csr_src[k + 2 + sub];
    int j2 = csr_src[k + 4 + sub];
    int j3 = csr_src[k + 6 + sub];
    f16x8 u0 = *reinterpret_cast<const f16x8*>(nb + (size_t)j0 * HDIM + c);
    f16x8 u1 = *reinterpret_cast<const f16x8*>(nb + (size_t)j1 * HDIM + c);
    f16x8 u2 = *reinterpret_cast<const f16x8*>(nb + (size_t)j2 * HDIM + c);
    f16x8 u3 = *reinterpret_cast<const f16x8*>(nb + (size_t)j3 * HDIM + c);
    #pragma unroll
    for (int q = 0; q < 8; ++q)
      acc[q] += ((float)u0[q] + (float)u1[q]) + ((float)u2[q] + (float)u3[q]);
  }
  for (; k < e; k += 2) {
    int j = k + sub;
    if (j < e) {
      f16x8 u = *reinterpret_cast<const f16x8*>(nb + (size_t)csr_src[j] * HDIM + c);
      #pragma unroll
      for (int q = 0; q < 8; ++q) acc[q] += (float)u[q];
    }
  }
  #pragma unroll
  for (int q = 0; q < 8; ++q) acc[q] += __shfl_xor(acc[q], 16, 64);
  if (sub == 0) {
    f16x8 o;
    #pragma unroll
    for (int q = 0; q < 8; ++q) o[q] = (f16)acc[q];
    __builtin_nontemporal_store(
        o, reinterpret_cast<f16x8*>(dst + (size_t)node * HDIM + c));
  }
}

// wave = 1 node, 4 edge-slots (sub=lane>>4), f16x8 per lane.
__global__ __launch_bounds__(256) void pull1_kernel(
    const u16* __restrict__ csr_src, const int* __restrict__ offs,
    const f16* __restrict__ cb, f16* __restrict__ Ctot, int N) {
  const int node = blockIdx.x * 4 + (threadIdx.x >> 6);
  if (node >= N) return;
  const int lane = threadIdx.x & 63;
  const int sub = lane >> 4;
  const int c = (lane & 15) << 3;
  const int s = offs[node];
  const int e = offs[node + 1];
  float acc[8];
  if (sub == 0) {
    f16x8 sv = *reinterpret_cast<const f16x8*>(cb + (size_t)node * HDIM + c);
    #pragma unroll
    for (int q = 0; q < 8; ++q) acc[q] = (float)sv[q];
  } else {
    #pragma unroll
    for (int q = 0; q < 8; ++q) acc[q] = 0.f;
  }
  int k = s;
  for (; k + 16 <= e; k += 16) {
    int j0 = csr_src[k + sub];
    int j1 = csr_src[k + 4 + sub];
    int j2 = csr_src[k + 8 + sub];
    int j3 = csr_src[k + 12 + sub];
    f16x8 u0 = *reinterpret_cast<const f16x8*>(cb + (size_t)j0 * HDIM + c);
    f16x8 u1 = *reinterpret_cast<const f16x8*>(cb + (size_t)j1 * HDIM + c);
    f16x8 u2 = *reinterpret_cast<const f16x8*>(cb + (size_t)j2 * HDIM + c);
    f16x8 u3 = *reinterpret_cast<const f16x8*>(cb + (size_t)j3 * HDIM + c);
    #pragma unroll
    for (int q = 0; q < 8; ++q)
      acc[q] += ((float)u0[q] + (float)u1[q]) + ((float)u2[q] + (float)u3[q]);
  }
  for (; k + 8 <= e; k += 8) {
    int j0 = csr_src[k + sub];
    int j1 = csr_src[k + 4 + sub];
    f16x8 u0 = *reinterpret_cast<const f16x8*>(cb + (size_t)j0 * HDIM + c);
    f16x8 u1 = *reinterpret_cast<const f16x8*>(cb + (size_t)j1 * HDIM + c);
    #pragma unroll
    for (int q = 0; q < 8; ++q) acc[q] += (float)u0[q] + (float)u1[q];
  }
  for (; k < e; k += 4) {
    int j = k + sub;
    if (j < e) {
      f16x8 u = *reinterpret_cast<const f16x8*>(cb + (size_t)csr_src[j] * HDIM + c);
      #pragma unroll
      for (int q = 0; q < 8; ++q) acc[q] += (float)u[q];
    }
  }
  #pragma unroll
  for (int q = 0; q < 8; ++q) {
    acc[q] += __shfl_xor(acc[q], 16, 64);
    acc[q] += __shfl_xor(acc[q], 32, 64);
  }
  if (sub == 0) {
    f16x8 o;
    #pragma unroll
    for (int q = 0; q < 8; ++q) o[q] = (f16)acc[q];
    __builtin_nontemporal_store(
        o, reinterpret_cast<f16x8*>(Ctot + (size_t)node * HDIM + c));
  }
}

// ================= fused MFMA gate GEMM (z, r, h-partial in one pass) ======
__device__ __forceinline__ void mfma_tile(
    const f16* As, const f16* Ws, int wr, int wc, int ln15, int quad,
    f32x4 (&acc)[2][4]) {
  #pragma unroll
  for (int s = 0; s < 4; ++s) {
    f16x8 a0 = *reinterpret_cast<const f16x8*>(
        &As[(wr * 32 + ln15) * 136 + s * 32 + quad * 8]);
    f16x8 a1 = *reinterpret_cast<const f16x8*>(
        &As[(wr * 32 + 16 + ln15) * 136 + s * 32 + quad * 8]);
    #pragma unroll
    for (int ni = 0; ni < 4; ++ni) {
      f16x8 bf = *reinterpret_cast<const f16x8*>(
          &Ws[(wc * 64 + ni * 16 + ln15) * 136 + s * 32 + quad * 8]);
      acc[0][ni] = __builtin_amdgcn_mfma_f32_16x16x32_f16(a0, bf, acc[0][ni], 0, 0, 0);
      acc[1][ni] = __builtin_amdgcn_mfma_f32_16x16x32_f16(a1, bf, acc[1][ni], 0, 0, 0);
    }
  }
}

__global__ __launch_bounds__(256, 3) void gemm3_kernel(
    const f16* __restrict__ A, const f16* __restrict__ Bh,
    const f16* __restrict__ WT, const float* __restrict__ b,
    const f16* __restrict__ hb, f16* __restrict__ zb,
    f16* __restrict__ cb, float* __restrict__ hpre, int N) {
  __shared__ f16 As[64 * 136];
  __shared__ f16 Ws[128 * 136];
  const int t = threadIdx.x;
  const int w = t >> 6, wr = w >> 1, wc = w & 1;
  const int lane = t & 63, ln15 = lane & 15, quad = lane >> 4;
  const int row0 = blockIdx.x * 64;
  f32x4 accZ[2][4], accR[2][4], accH[2][4];
  #pragma unroll
  for (int i = 0; i < 2; ++i)
    #pragma unroll
    for (int j = 0; j < 4; ++j) {
      accZ[i][j] = (f32x4){0.f, 0.f, 0.f, 0.f};
      accR[i][j] = (f32x4){0.f, 0.f, 0.f, 0.f};
      accH[i][j] = (f32x4){0.f, 0.f, 0.f, 0.f};
    }

  // ---- stage A (x-aggregate) ----
  #pragma unroll
  for (int i = 0; i < 4; ++i) {
    int flat = i * 256 + t;
    int r = flat >> 4;
    int o = (flat & 15) * 8;
    int row = row0 + r;
    f16x8 v{};
    if (row < N) v = *reinterpret_cast<const f16x8*>(A + (size_t)row * HDIM + o);
    *reinterpret_cast<f16x8*>(&As[r * 136 + o]) = v;
  }
  #pragma unroll
  for (int g = 0; g < 3; ++g) {          // gates 0,2,4 against x-aggregate
    const f16* __restrict__ wp = WT + (size_t)(g * 2) * HDIM * HDIM;
    __syncthreads();
    #pragma unroll
    for (int i = 0; i < 8; ++i) {
      int flat = i * 256 + t;
      int n = flat >> 4;
      int o = (flat & 15) * 8;
      *reinterpret_cast<f16x8*>(&Ws[n * 136 + o]) =
          *reinterpret_cast<const f16x8*>(wp + (size_t)n * HDIM + o);
    }
    __syncthreads();
    if (g == 0) mfma_tile(As, Ws, wr, wc, ln15, quad, accZ);
    else if (g == 1) mfma_tile(As, Ws, wr, wc, ln15, quad, accR);
    else mfma_tile(As, Ws, wr, wc, ln15, quad, accH);
  }
  __syncthreads();
  // ---- restage As with Bh (h-aggregate) ----
  #pragma unroll
  for (int i = 0; i < 4; ++i) {
    int flat = i * 256 + t;
    int r = flat >> 4;
    int o = (flat & 15) * 8;
    int row = row0 + r;
    f16x8 v{};
    if (row < N) v = *reinterpret_cast<const f16x8*>(Bh + (size_t)row * HDIM + o);
    *reinterpret_cast<f16x8*>(&As[r * 136 + o]) = v;
  }
  #pragma unroll
  for (int g = 0; g < 2; ++g) {          // gates 1,3 against h-aggregate
    const f16* __restrict__ wp = WT + (size_t)(g * 2 + 1) * HDIM * HDIM;
    __syncthreads();
    #pragma unroll
    for (int i = 0; i < 8; ++i) {
      int flat = i * 256 + t;
      int n = flat >> 4;
      int o = (flat & 15) * 8;
      *reinterpret_cast<f16x8*>(&Ws[n * 136 + o]) =
          *reinterpret_cast<const f16x8*>(wp + (size_t)n * HDIM + o);
    }
    __syncthreads();
    if (g == 0) mfma_tile(As, Ws, wr, wc, ln15, quad, accZ);
    else mfma_tile(As, Ws, wr, wc, ln15, quad, accR);
  }

  // ---- epilogue: z, c=sigmoid(r)*h, hpre ----
  #pragma unroll
  for (int ni = 0; ni < 4; ++ni) {
    const int col = wc * 64 + ni * 16 + ln15;
    float bz = b[0 * HDIM + col] + b[1 * HDIM + col];
    float br = b[2 * HDIM + col] + b[3 * HDIM + col];
    float bh = b[4 * HDIM + col];
    #pragma unroll
    for (int mi = 0; mi < 2; ++mi) {
      #pragma unroll
      for (int r = 0; r < 4; ++r) {
        int row = row0 + wr * 32 + mi * 16 + quad * 4 + r;
        if (row >= N) continue;
        size_t idx = (size_t)row * HDIM + col;
        zb[idx] = (f16)(accZ[mi][ni][r] + bz);
        float rv = accR[mi][ni][r] + br;
        float rg = 1.f / (1.f + expf(-rv));
        cb[idx] = (f16)(rg * (float)hb[idx]);
        hpre[idx] = accH[mi][ni][r] + bh;
      }
    }
  }
}

// ================= MFMA final GEMM + GRU combine =================
__global__ __launch_bounds__(256, 3) void gemm_final_kernel(
    const f16* __restrict__ Ctot, const f16* __restrict__ WT5,
    const float* __restrict__ b5, const f16* __restrict__ zb,
    const float* __restrict__ hi, float* __restrict__ outi,
    f16* __restrict__ xb, int N) {
  __shared__ f16 As[64 * 136];
  __shared__ f16 Ws[128 * 136];
  const int t = threadIdx.x;
  const int w = t >> 6, wr = w >> 1, wc = w & 1;
  const int lane = t & 63, ln15 = lane & 15, quad = lane >> 4;
  const int row0 = blockIdx.x * 64;
  f32x4 acc[2][4];
  #pragma unroll
  for (int i = 0; i < 2; ++i)
    #pragma unroll
    for (int j = 0; j < 4; ++j) acc[i][j] = (f32x4){0.f, 0.f, 0.f, 0.f};

  #pragma unroll
  for (int i = 0; i < 4; ++i) {
    int flat = i * 256 + t;
    int r = flat >> 4;
    int o = (flat & 15) * 8;
    int row = row0 + r;
    f16x8 v{};
    if (row < N) v = *reinterpret_cast<const f16x8*>(Ctot + (size_t)row * HDIM + o);
    *reinterpret_cast<f16x8*>(&As[r * 136 + o]) = v;
  }
  #pragma unroll
  for (int i = 0; i < 8; ++i) {
    int flat = i * 256 + t;
    int n = flat >> 4;
    int o = (flat & 15) * 8;
    *reinterpret_cast<f16x8*>(&Ws[n * 136 + o]) =
        *reinterpret_cast<const f16x8*>(WT5 + (size_t)n * HDIM + o);
  }
  __syncthreads();
  mfma_tile(As, Ws, wr, wc, ln15, quad, acc);

  #pragma unroll
  for (int ni = 0; ni < 4; ++ni) {
    const int col = wc * 64 + ni * 16 + ln15;
    float bias = b5[col];
    #pragma unroll
    for (int mi = 0; mi < 2; ++mi) {
      #pragma unroll
      for (int r = 0; r < 4; ++r) {
        int row = row0 + wr * 32 + mi * 16 + quad * 4 + r;
        if (row >= N) continue;
        size_t idx = (size_t)row * HDIM + col;
        float v = acc[mi][ni][r] + bias + outi[idx];  // + hpre
        float ht = tanhf(v);
        float z = 1.f / (1.f + expf(-(float)zb[idx]));
        float o = z * hi[idx] + (1.f - z) * ht;
        outi[idx] = o;
        xb[idx] = (f16)o;
      }
    }
  }
}

extern "C" void kernel_launch(void* const* d_in, const int* in_sizes, int n_in,
                              void* d_out, int out_size, void* d_ws, size_t ws_size,
                              hipStream_t stream) {
  const float* inp = (const float*)d_in[0];
  const int*   edg = (const int*)d_in[1];
  const float* h   = (const float*)d_in[2];
  const float* W   = (const float*)d_in[3];
  const float* b   = (const float*)d_in[4];
  float* out = (float*)d_out;

  const int NH = in_sizes[0];      // N*H
  const int N  = NH / HDIM;
  const int E  = in_sizes[1] / 2;
  const int L  = in_sizes[2] / NH;

  f16* Af   = (f16*)d_ws;               // A aggregate / Ctot (reused)
  f16* Bhf  = Af + (size_t)NH;          // Bh aggregate
  f16* zbuf = Bhf + (size_t)NH;         // zpre
  f16* cbuf = zbuf + (size_t)NH;        // r*h
  f16* xbuf = cbuf + (size_t)NH;        // x f16
  f16* hbuf = xbuf + (size_t)NH;        // h_i f16
  f16* WT   = hbuf + (size_t)NH;        // L*6*H*H transposed f16 weights
  int* deg     = (int*)(WT + (size_t)L * 6 * HDIM * HDIM);
  int* offs    = deg + N;               // N+1
  int* bsum    = offs + (N + 1);        // 256
  int* boff    = bsum + 256;            // 256
  u16* rank    = (u16*)(boff + 256);    // E
  u16* csr_src = rank + (size_t)E;      // E
  // bucket counters: N*16 ints, only live during CSR build -> overlay on Af
  int* cnt     = (int*)Af;

  const int eblocks = (E + 255) / 256;
  const int fblocks = (E + 1023) / 1024;
  const int nodeblocks = (N + 3) / 4;
  const int nsblocks = (N + 255) / 256;
  const int n4 = NH / 4;
  const int cvblocks = (n4 + 255) / 256;
  const int rowblocks = (N + 63) / 64;
  const int chunk = (N + 255) / 256;    // <=256 requires N<=65536

  // ---- one-time per call: CSR build (approx src-sorted), transpose, f16 ----
  hipMemsetAsync(cnt, 0, (size_t)N * 16 * sizeof(int), stream);
  hipLaunchKernelGGL(degrank_kernel, dim3(eblocks), dim3(256), 0, stream,
                     edg, cnt, rank, E);
  hipLaunchKernelGGL(nodescan_kernel, dim3(nsblocks), dim3(256), 0, stream,
                     cnt, deg, N);
  hipLaunchKernelGGL(scan_part_kernel, dim3(256), dim3(256), 0, stream,
                     deg, bsum, N, chunk);
  hipLaunchKernelGGL(scan_top_kernel, dim3(1), dim3(256), 0, stream,
                     bsum, boff, offs, N);
  hipLaunchKernelGGL(scan_fin_kernel, dim3(256), dim3(256), 0, stream,
                     deg, boff, offs, N, chunk);
  hipLaunchKernelGGL(fill_kernel, dim3(fblocks), dim3(256), 0, stream,
                     edg, offs, cnt, rank, csr_src, E);
  hipLaunchKernelGGL(transw_kernel, dim3(16, L * 6), dim3(256), 0, stream,
                     W, WT);
  hipLaunchKernelGGL(convh_kernel, dim3(cvblocks), dim3(256), 0, stream,
                     inp, xbuf, n4);

  for (int i = 0; i < L; ++i) {
    const float* hi = h + (size_t)i * NH;
    const f16* WTi = WT + (size_t)i * 6 * HDIM * HDIM;
    const float* bi = b + (size_t)i * 6 * HDIM;
    float* outi = out + (size_t)i * NH;

    hipLaunchKernelGGL(convh_kernel, dim3(cvblocks), dim3(256), 0, stream,
                       hi, hbuf, n4);
    hipLaunchKernelGGL(pull2_kernel, dim3(nodeblocks), dim3(256), 0, stream,
                       csr_src, offs, xbuf, hbuf, Af, Bhf, N);
    hipLaunchKernelGGL(gemm3_kernel, dim3(rowblocks), dim3(256), 0, stream,
                       Af, Bhf, WTi, bi, hbuf, zbuf, cbuf, outi, N);
    hipLaunchKernelGGL(pull1_kernel, dim3(nodeblocks), dim3(256), 0, stream,
                       csr_src, offs, cbuf, Af, N);   // Af reused as Ctot
    hipLaunchKernelGGL(gemm_final_kernel, dim3(rowblocks), dim3(256), 0, stream,
                       Af, WTi + (size_t)5 * HDIM * HDIM, bi + 5 * HDIM,
                       zbuf, hi, outi, xbuf, N);
  }
}